// Round 11
// baseline (758.949 us; speedup 1.0000x reference)
//
#include <hip/hip_runtime.h>
#include <math.h>

typedef unsigned short u16;
typedef unsigned int u32;
typedef __attribute__((ext_vector_type(8))) short bf16x8;
typedef __attribute__((ext_vector_type(4))) float f32x4;

#define S_LEN 2048
#define HID 4096
#define NH 32
#define NKV 8
#define HD 128
#define QS 6144  // fused qkv row stride (4096 Q | 1024 K | 1024 V)

__device__ __forceinline__ u16 f2bf(float f) {
  u32 u = __float_as_uint(f);
  u32 r = (u + 0x7FFFu + ((u >> 16) & 1u)) >> 16;
  return (u16)r;
}
__device__ __forceinline__ float bf2f(u16 v) {
  return __uint_as_float(((u32)v) << 16);
}
__device__ __forceinline__ f32x4 mfma16(bf16x8 a, bf16x8 b, f32x4 c) {
  return __builtin_amdgcn_mfma_f32_16x16x32_bf16(a, b, c, 0, 0, 0);
}
// async global->LDS, 16B per lane. LDS dest is wave-uniform base + lane*16.
__device__ __forceinline__ void async16(const u16* g, u16* l) {
  __builtin_amdgcn_global_load_lds(
      (__attribute__((address_space(1))) void*)g,
      (__attribute__((address_space(3))) void*)l, 16, 0, 0);
}
#if __has_builtin(__builtin_amdgcn_exp2f)
#define EXP2(x) __builtin_amdgcn_exp2f(x)
#else
#define EXP2(x) exp2f(x)
#endif

#define VMC(n) asm volatile("s_waitcnt vmcnt(" #n ")" ::: "memory")
#define LGKM0 asm volatile("s_waitcnt lgkmcnt(0)" ::: "memory")
#define BAR __builtin_amdgcn_s_barrier()

// ---------------- fp32 -> bf16 for hidden_states only ------------------------
__global__ __launch_bounds__(256) void conv_hs(const float* __restrict__ hs,
                                               u16* __restrict__ dst) {
  int i = blockIdx.x * 256 + threadIdx.x;
  float4 v = ((const float4*)hs)[i];
  ushort4 o;
  o.x = f2bf(v.x); o.y = f2bf(v.y); o.z = f2bf(v.z); o.w = f2bf(v.w);
  ((ushort4*)dst)[i] = o;
}

// ---------------- 256xBN 4-phase GEMM, fp32-B direct, depth-2 B pipeline ----
// C[M,N] = A[M,K] * B[N,K]^T.  A bf16 via gload_lds (R7 path, unchanged);
// B fp32 read DIRECTLY from the weight tensors, reg-staged with TWO named
// register buffers (bvE/bvO) so no wait ever targets the newest vmem group
// (R9's failure: wrB right after its ldB forced vmcnt(0), draining the A
// prefetch and exposing full HBM latency):
//   pre-ph2: ldBE(t+2); STAll(t+2,d0); VMC(10)  [drains A(t+1), 10 newer]
//   pre-ph4: wrBE->d0 (loads 2 phases old; compiler wait vmcnt(4/10), not 0)
//            ldBO(t+3); STAll(t+3,d1); VMC(10)  [drains A(t+2)]
//   pre-ph1: wrBO->d1 (loads 1 phase old; steady-state wait vmcnt(4))
// LGKM0 before ph1/ph4 entry barriers publishes cross-wave ds_writes.
// De-caged scheduling otherwise (R7 win): no sched_barrier, no setprio.
// B LDS layout identical to the bf16 path: slot = chunk ^ (row&7), so the
// DS-read/MFMA side is byte-for-byte R7.  B rows select among W0|W1|W2 at
// nb1/nb2 (per-lane pointer, computed once).
// Grid = 8 * (N/BN); M == 2048 -> 8 M-tiles; %8 == 0 for the XCD swizzle.

#define DSA(dst, qi, d)                                                    \
  {                                                                        \
    const u16* p_ = As + (d)*16384 + (wm * 64 + (qi)*32 + cl) * 64;        \
    _Pragma("unroll") for (int ii = 0; ii < 2; ii++)                       \
        _Pragma("unroll") for (int kk = 0; kk < 2; kk++)                   \
            dst[ii][kk] =                                                  \
        *(const bf16x8*)(p_ + ii * 1024 + ((c0 ^ (kk << 2)) << 3));        \
  }

#define DSB(dst, qj, d)                                                    \
  {                                                                        \
    const u16* p_ =                                                        \
        Bs + (d)*BSTR + (wn * (BN / 2) + (qj) * (BN / 4) + cl) * 64;       \
    _Pragma("unroll") for (int jj = 0; jj < NJ; jj++)                      \
        _Pragma("unroll") for (int kk = 0; kk < 2; kk++)                   \
            dst[jj][kk] =                                                  \
        *(const bf16x8*)(p_ + jj * 1024 + ((c0 ^ (kk << 2)) << 3));        \
  }

// kk outermost: consecutive MFMAs hit distinct acc regs
#define MM(qi, qj, asrc, bsrc)                                             \
  {                                                                        \
    _Pragma("unroll") for (int kk = 0; kk < 2; kk++)                       \
        _Pragma("unroll") for (int ii = 0; ii < 2; ii++)                   \
            _Pragma("unroll") for (int jj = 0; jj < NJ; jj++)              \
                acc[(qi)*2 + ii][(qj)*NJ + jj] =                           \
        mfma16(asrc[ii][kk], bsrc[jj][kk], acc[(qi)*2 + ii][(qj)*NJ + jj]);\
  }

#define PH2(MMA1, MMA2)                                          \
  {                                                              \
    BAR;                                                         \
    MMA1; MMA2;                                                  \
    BAR;                                                         \
  }

template <int NJ>
__global__ __launch_bounds__(512, 2) void gemm4p(
    const u16* __restrict__ A, const float* __restrict__ W0,
    const float* __restrict__ W1, const float* __restrict__ W2,
    int nb1, int nb2, u16* __restrict__ Cb, float* __restrict__ Cf,
    int N, int K) {
  constexpr int BN = NJ * 64;
  constexpr int BSTR = BN * 64;  // u16 per B dbuf
  extern __shared__ u16 lds[];
  u16* As = lds;           // [2][256*64]
  u16* Bs = lds + 32768;   // [2][BN*64]
  const int tid = threadIdx.x;
  const int lane = tid & 63, wv = tid >> 6;
  const int cl = lane & 15, qd = lane >> 4;
  const int wm = wv >> 1, wn = wv & 1;  // 4M x 2N waves
  const int c0 = qd ^ (cl & 7);

  // XCD-aware block swizzle (grid %8==0), decode M-fast (M-tiles == 8)
  const int cpx = gridDim.x >> 3;
  const int swz = (blockIdx.x & 7) * cpx + (blockIdx.x >> 3);
  const int m0 = (swz & 7) * 256;
  const int n0 = (swz >> 3) * BN;

  // A staging offsets (bf16 gload_lds, pre-swizzled source)
  u32 aof[4];
#pragma unroll
  for (int q = 0; q < 4; q++) {
    int r = q * 64 + wv * 8 + (lane >> 3);
    int c = (lane & 7) ^ (r & 7);
    aof[q] = (u32)(m0 + r) * K + c * 8;
  }
  const int sbo = wv * 512;  // wave-uniform LDS stage offset

  // B staging geometry: round rq covers row rl = rq*32 + (tid>>4),
  // f32-chunk gc = tid&15 (16B).  bf16 chunk c = gc>>1, half = gc&1;
  // swizzled ds_write slot = c ^ (rl&7).
  const float* bptr[2 * NJ];
  u32 bwr[2 * NJ];
#pragma unroll
  for (int rq = 0; rq < 2 * NJ; rq++) {
    int rl = rq * 32 + (tid >> 4);
    int gc = tid & 15;
    int row = n0 + rl;
    const float* p = (row < nb1) ? (W0 + (size_t)row * K)
                   : (row < nb2) ? (W1 + (size_t)(row - nb1) * K)
                                 : (W2 + (size_t)(row - nb2) * K);
    bptr[rq] = p + gc * 4;
    bwr[rq] = (u32)rl * 64 + (((gc >> 1) ^ (rl & 7)) * 8) + ((gc & 1) * 4);
  }

  auto STAll = [&](int tt, int d) {  // stage full A K-tile (4 gload_lds)
#pragma unroll
    for (int q = 0; q < 4; q++)
      async16(A + (size_t)tt * 64 + aof[q], As + d * 16384 + q * 4096 + sbo);
  };

  float4 bvE[2 * NJ], bvO[2 * NJ];  // two NAMED buffers (static indexing)
  auto ldBE = [&]() {
#pragma unroll
    for (int rq = 0; rq < 2 * NJ; rq++) {
      bvE[rq] = *(const float4*)bptr[rq];
      bptr[rq] += 64;  // advance one K-tile (64 f32)
    }
  };
  auto ldBO = [&]() {
#pragma unroll
    for (int rq = 0; rq < 2 * NJ; rq++) {
      bvO[rq] = *(const float4*)bptr[rq];
      bptr[rq] += 64;
    }
  };
  auto wrBE = [&](int d) {
#pragma unroll
    for (int rq = 0; rq < 2 * NJ; rq++) {
      uint2 wd;
      wd.x = (u32)f2bf(bvE[rq].x) | ((u32)f2bf(bvE[rq].y) << 16);
      wd.y = (u32)f2bf(bvE[rq].z) | ((u32)f2bf(bvE[rq].w) << 16);
      *(uint2*)(Bs + d * BSTR + bwr[rq]) = wd;  // ds_write_b64
    }
  };
  auto wrBO = [&](int d) {
#pragma unroll
    for (int rq = 0; rq < 2 * NJ; rq++) {
      uint2 wd;
      wd.x = (u32)f2bf(bvO[rq].x) | ((u32)f2bf(bvO[rq].y) << 16);
      wd.y = (u32)f2bf(bvO[rq].z) | ((u32)f2bf(bvO[rq].w) << 16);
      *(uint2*)(Bs + d * BSTR + bwr[rq]) = wd;
    }
  };

  f32x4 acc[4][2 * NJ];
  f32x4 zz = {0.f, 0.f, 0.f, 0.f};
#pragma unroll
  for (int i = 0; i < 4; i++)
#pragma unroll
    for (int j = 0; j < 2 * NJ; j++) acc[i][j] = zz;
  bf16x8 A0r[2][2], A1r[2][2], B0r[NJ][2], B1r[NJ][2];

  const int NT = K >> 6;  // 64-wide K-tiles; NT even, >= 4

  // prologue: ldB(0)->bvE; A(0)->d0, A(1)->d1; wrB(0)->d0 (compiler waits
  // vmcnt(8): retires ldB(0), keeps A(0),A(1)); ldB(1)->bvO;
  // VMC(10) drains A(0) (newer: A(1)4 + ldB(1)6 = 10).
  ldBE();
  STAll(0, 0);
  STAll(1, 1);
  wrBE(0);
  ldBO();
  VMC(10);
  LGKM0;  // publish B(0) ds_writes
  BAR;

  for (int it = 0; it < (NT >> 1); ++it) {
    const int t = it * 2;          // tiles t (dbuf0), t+1 (dbuf1)
    const bool s2 = (t + 2) < NT;  // NT even => also guards t+3
    // pre-ph1: wrB(t+1)->d1 from bvO (1 phase old; steady-state wait
    //          vmcnt(4), A prefetch survives) | ds reads dbuf0
    wrBO(1);
    DSA(A0r, 0, 0); DSA(A1r, 1, 0); DSB(B0r, 0, 0);
    LGKM0;  // publish d1 writes (and drain own frag reads)
    PH2(MM(0, 0, A0r, B0r), MM(1, 0, A1r, B0r));
    // pre-ph2: ds B1(dbuf0) | ldBE(t+2) | A(t+2) gload -> d0
    //          VMC(10): drains A(t+1) (newer: ldBE 6 + A(t+2) 4)
    DSB(B1r, 1, 0);
    if (s2) {
      ldBE();
      STAll(t + 2, 0);
      VMC(10);
    } else {
      VMC(0);
    }
    PH2(MM(0, 1, A0r, B1r), MM(1, 1, A1r, B1r));
    // pre-ph3: ds reads dbuf1 (A(t+1) landed via VMC@pre-ph2)
    DSA(A0r, 0, 1); DSA(A1r, 1, 1); DSB(B0r, 0, 1);
    PH2(MM(0, 0, A0r, B0r), MM(1, 0, A1r, B0r));
    // pre-ph4: ds B1(dbuf1) | wrB(t+2)->d0 from bvE (2 phases old) |
    //          ldBO(t+3) | A(t+3) gload -> d1
    //          VMC(10): drains A(t+2) (newer: ldBO 6 + A(t+3) 4)
    DSB(B1r, 1, 1);
    if (s2) {
      wrBE(0);
      ldBO();
      STAll(t + 3, 1);
      VMC(10);
    } else {
      VMC(0);
    }
    LGKM0;  // publish d0 writes (and drain own frag reads)
    PH2(MM(0, 1, A0r, B1r), MM(1, 1, A1r, B1r));
  }

  // epilogue: C-write (C/D layout: col=lane&15, row=(lane>>4)*4+reg)
#pragma unroll
  for (int i = 0; i < 4; i++)
#pragma unroll
    for (int j = 0; j < 2 * NJ; j++) {
      int row = m0 + wm * 64 + i * 16 + qd * 4;
      int col = n0 + wn * (BN / 2) + (j / NJ) * (BN / 4) + (j % NJ) * 16 + cl;
#pragma unroll
      for (int r = 0; r < 4; r++) {
        float v = acc[i][j][r];
        if (Cb) Cb[(size_t)(row + r) * N + col] = f2bf(v);
        else    Cf[(size_t)(row + r) * N + col] = v;
      }
    }
}

// ---------------- fused RoPE + L2 norm (in place, bf16, strided) -------------
__global__ __launch_bounds__(256) void rope_l2norm(
    u16* __restrict__ x, const int* __restrict__ pos_ids,
    const float* __restrict__ scale, int hmask, int hshift, int stride) {
  const int lane = threadIdx.x & 63;
  const int wv = threadIdx.x >> 6;
  const int idx = blockIdx.x * 4 + wv;
  const int s = idx >> hshift;
  const int h = idx & hmask;
  u16* p = x + (size_t)s * stride + h * HD;
  const float pos = (float)pos_ids[s];
  const float inv = expf((float)lane * -0.20503692777194264f);  // 5e5^(-d/64)
  float sn, cs;
  sincosf(pos * inv, &sn, &cs);
  float a = bf2f(p[lane]);
  float b = bf2f(p[lane + 64]);
  float ra = a * cs - b * sn;
  float rb = b * cs + a * sn;
  float ss = ra * ra + rb * rb;
#pragma unroll
  for (int off = 32; off >= 1; off >>= 1) ss += __shfl_xor(ss, off, 64);
  float rd = 1.0f / (sqrtf(ss) + 1e-6f);
  p[lane] = f2bf(scale[lane] * ra * rd);
  p[lane + 64] = f2bf(scale[lane + 64] * rb * rd);
}

// ---------------- V transpose: qkv V-cols [2048][1024@QS] -> [1024][2048] ----
__global__ __launch_bounds__(256) void transpose_v(const u16* __restrict__ v,
                                                   u16* __restrict__ vt) {
  __shared__ u16 t[64][65];
  const int r = threadIdx.x >> 6;
  const int c = threadIdx.x & 63;
  const int s0 = blockIdx.x * 64, d0 = blockIdx.y * 64;
#pragma unroll
  for (int i = 0; i < 16; i++) {
    int row = i * 4 + r;
    t[row][c] = v[(size_t)(s0 + row) * QS + d0 + c];
  }
  __syncthreads();
#pragma unroll
  for (int i = 0; i < 16; i++) {
    int row = i * 4 + r;
    vt[(size_t)(d0 + row) * S_LEN + s0 + c] = t[c][row];
  }
}

// ---------------- causal flash attention, Q-tile 128, 8 waves ----------------
// Work-balanced (qbi, 15-qbi) pairs, grid 8 x 32 = 256 blocks = 1/CU.
// K/V double-buffered in dynamic LDS; stage(kt+1) issued BEFORE compute(kt);
// one vmcnt(0)+barrier per tile.  No sched fences (compiler-scheduled).
#define PLD 68

__global__ __launch_bounds__(512) void flash_attn(
    const u16* __restrict__ QKV, const u16* __restrict__ Vt,
    u16* __restrict__ O) {
  extern __shared__ u16 alds[];
  u16* Ks = alds;           // [2][64*128]  slot = row*16 + (g ^ (row&15))
  u16* Vs = alds + 16384;   // [2][128*64]  slot = row*8  + (g ^ (row&7))
  u16* Ps = alds + 32768;   // [128][PLD]
  const int tid = threadIdx.x;
  const int lane = tid & 63, wv = tid >> 6;  // wv in [0,8)
  const int cl = lane & 15, qd = lane >> 4;
  const int h = blockIdx.y;
  const int kvh = h >> 2;
  const float es = 0.12751629240081506f;  // (1/sqrt(128)) * log2(e)

  const u16* Kbase = QKV + 4096 + kvh * HD;          // key rows, stride QS
  const u16* Vbase = Vt + (size_t)kvh * HD * S_LEN;  // [d][s], stride S_LEN

  auto stage = [&](int kt, int d) {
#pragma unroll
    for (int q = 0; q < 2; q++) {
      int c = q * 512 + wv * 64 + lane;
      int kr = c >> 4, kg = (c & 15) ^ (kr & 15);
      async16(Kbase + (size_t)(kt * 64 + kr) * QS + kg * 8,
              Ks + d * 8192 + (q * 512 + wv * 64) * 8);
      int vr = c >> 3, vg = (c & 7) ^ (vr & 7);
      async16(Vbase + (size_t)vr * S_LEN + kt * 64 + vg * 8,
              Vs + d * 8192 + (q * 512 + wv * 64) * 8);
    }
  };

  for (int half = 0; half < 2; half++) {
    const int qbi = half ? (15 - (int)blockIdx.x) : (int)blockIdx.x;
    const int q0 = qbi * 128;

    // Q fragments straight from global; wave wv owns q-rows q0+wv*16 .. +15
    bf16x8 aQ[4];
    {
      const u16* qrow =
          QKV + (size_t)(q0 + wv * 16 + cl) * QS + h * HD + qd * 8;
#pragma unroll
      for (int kk = 0; kk < 4; kk++) aQ[kk] = *(const bf16x8*)(qrow + kk * 32);
    }

    f32x4 oacc[8];
    f32x4 zz = {0.f, 0.f, 0.f, 0.f};
#pragma unroll
    for (int n = 0; n < 8; n++) oacc[n] = zz;
    float lsum[4] = {0.f, 0.f, 0.f, 0.f};

    const int row_min = q0 + wv * 16;
    const int ktmax = 2 * qbi + 1;  // >= 1 always

    int cur = 0;
    stage(0, 0);
    for (int kt = 0; kt <= ktmax; kt++) {
      if (kt < ktmax) stage(kt + 1, cur ^ 1);  // issue-early
      if (kt == 0) {
        VMC(4);  // tile0 landed; tile1's 4 loads stay in flight
        BAR;
      }
      const int koff = cur * 8192;

      if (kt * 64 <= row_min + 15) {  // wave not fully above the diagonal
        // S = Q K^T (this wave: 16 q-rows x 64 keys); kk outer -> indep runs
        f32x4 sacc[4];
#pragma unroll
        for (int j = 0; j < 4; j++) sacc[j] = zz;
#pragma unroll
        for (int kk = 0; kk < 4; kk++) {
#pragma unroll
          for (int j = 0; j < 4; j++) {
            int row = j * 16 + cl;
            int ch = (kk * 4 + qd) ^ (row & 15);
            bf16x8 bK = *(const bf16x8*)&Ks[koff + row * 128 + ch * 8];
            sacc[j] = mfma16(aQ[kk], bK, sacc[j]);
          }
        }

        float pm[4][4];
        if (kt * 64 + 63 > row_min) {  // diagonal tile: causal mask
          const int grow = row_min + qd * 4;
#pragma unroll
          for (int j = 0; j < 4; j++) {
            int gcol = kt * 64 + j * 16 + cl;
#pragma unroll
            for (int r = 0; r < 4; r++)
              pm[j][r] = (gcol <= grow + r) ? EXP2(sacc[j][r] * es) : 0.f;
          }
        } else {
#pragma unroll
          for (int j = 0; j < 4; j++)
#pragma unroll
            for (int r = 0; r < 4; r++) pm[j][r] = EXP2(sacc[j][r] * es);
        }
#pragma unroll
        for (int j = 0; j < 4; j++)
#pragma unroll
          for (int r = 0; r < 4; r++) lsum[r] += pm[j][r];

        // P: C-layout -> LDS (A-layout); wave-private strip, no block barrier
#pragma unroll
        for (int j = 0; j < 4; j++)
#pragma unroll
          for (int r = 0; r < 4; r++)
            Ps[(wv * 16 + qd * 4 + r) * PLD + j * 16 + cl] = f2bf(pm[j][r]);
        __asm__ volatile("s_waitcnt lgkmcnt(0)" ::: "memory");  // cross-lane

        // O += P V (n inner: dep distance 8)
#pragma unroll
        for (int kk = 0; kk < 2; kk++) {
          bf16x8 aP =
              *(const bf16x8*)&Ps[(wv * 16 + cl) * PLD + kk * 32 + qd * 8];
#pragma unroll
          for (int n = 0; n < 8; n++) {
            int row = n * 16 + cl;
            int ch = (kk * 4 + qd) ^ (row & 7);
            bf16x8 bV = *(const bf16x8*)&Vs[koff + row * 64 + ch * 8];
            oacc[n] = mfma16(aP, bV, oacc[n]);
          }
        }
      }

      VMC(0);  // stage(kt+1) drained (latency hidden under compute)
      BAR;
      cur ^= 1;
    }

    // reduce row sums across the 16-lane column group, write O
#pragma unroll
    for (int r = 0; r < 4; r++) {
#pragma unroll
      for (int off = 8; off >= 1; off >>= 1)
        lsum[r] += __shfl_xor(lsum[r], off, 64);
    }
#pragma unroll
    for (int r = 0; r < 4; r++) {
      float il = 1.0f / lsum[r];
      int row = row_min + qd * 4 + r;
#pragma unroll
      for (int n = 0; n < 8; n++)
        O[(size_t)row * HID + h * HD + n * 16 + cl] = f2bf(oacc[n][r] * il);
    }
  }
}

// ---------------- launch ----------------
extern "C" void kernel_launch(void* const* d_in, const int* in_sizes, int n_in,
                              void* d_out, int out_size, void* d_ws, size_t ws_size,
                              hipStream_t stream) {
  const float* hs = (const float*)d_in[0];
  const int* pos = (const int*)d_in[1];
  const float* Wq = (const float*)d_in[2];
  const float* Wk = (const float*)d_in[3];
  const float* Wv = (const float*)d_in[4];
  const float* Wo = (const float*)d_in[5];
  const float* qsc = (const float*)d_in[6];
  const float* ksc = (const float*)d_in[7];
  float* out = (float*)d_out;
  char* ws = (char*)d_ws;
  const size_t MB = 1u << 20;

  u16* hs_b  = (u16*)(ws + 0 * MB);   // 16 MB; reused for attention output
  u16* qkv_b = (u16*)(ws + 64 * MB);  // 24 MB: [2048][6144] = Q|K|V
  u16* vt_b  = (u16*)(ws + 88 * MB);  // 4 MB: V^T [1024][2048]
  u16* o_b   = hs_b;                  // hs dead after qkv gemm

  static bool attr_set = false;
  if (!attr_set) {
    hipFuncSetAttribute(reinterpret_cast<const void*>(&gemm4p<3>),
                        hipFuncAttributeMaxDynamicSharedMemorySize, 114688);
    hipFuncSetAttribute(reinterpret_cast<const void*>(&gemm4p<2>),
                        hipFuncAttributeMaxDynamicSharedMemorySize, 98304);
    hipFuncSetAttribute(reinterpret_cast<const void*>(&flash_attn),
                        hipFuncAttributeMaxDynamicSharedMemorySize, 82944);
    attr_set = true;
  }

  // hs fp32 -> bf16 (weights are consumed fp32 directly by the GEMMs)
  conv_hs<<<8192, 256, 0, stream>>>(hs, hs_b);

  // fused QKV projection: [2048][4096] x [6144][4096]^T -> [2048][6144]
  // B rows 0..4095 = Wq, 4096..5119 = Wk, 5120..6143 = Wv (fp32 direct)
  gemm4p<3><<<dim3(8 * (QS / 192)), 512, 114688, stream>>>(
      hs_b, Wq, Wk, Wv, 4096, 5120, qkv_b, nullptr, QS, HID);

  rope_l2norm<<<S_LEN * NH / 4, 256, 0, stream>>>(qkv_b, pos, qsc, NH - 1, 5, QS);
  rope_l2norm<<<S_LEN * NKV / 4, 256, 0, stream>>>(qkv_b + 4096, pos, ksc, NKV - 1, 3, QS);
  transpose_v<<<dim3(S_LEN / 64, (NKV * HD) / 64), 256, 0, stream>>>(qkv_b + 5120, vt_b);

  flash_attn<<<dim3(8, NH), 512, 82944, stream>>>(qkv_b, vt_b, o_b);

  // output projection: [2048][4096] x [4096][4096]^T -> f32 out (Wo fp32)
  gemm4p<2><<<dim3(8 * (HID / 128)), 512, 98304, stream>>>(
      o_b, Wo, Wo, Wo, HID, HID, nullptr, out, HID, HID);
}

// Round 12
// 455.185 us; speedup vs baseline: 1.6673x; 1.6673x over previous
//
#include <hip/hip_runtime.h>
#include <math.h>

typedef unsigned short u16;
typedef unsigned int u32;
typedef __attribute__((ext_vector_type(8))) short bf16x8;
typedef __attribute__((ext_vector_type(4))) float f32x4;

#define S_LEN 2048
#define HID 4096
#define NH 32
#define NKV 8
#define HD 128
#define QS 6144  // fused qkv row stride (4096 Q | 1024 K | 1024 V)

__device__ __forceinline__ u16 f2bf(float f) {
  u32 u = __float_as_uint(f);
  u32 r = (u + 0x7FFFu + ((u >> 16) & 1u)) >> 16;
  return (u16)r;
}
__device__ __forceinline__ float bf2f(u16 v) {
  return __uint_as_float(((u32)v) << 16);
}
__device__ __forceinline__ f32x4 mfma16(bf16x8 a, bf16x8 b, f32x4 c) {
  return __builtin_amdgcn_mfma_f32_16x16x32_bf16(a, b, c, 0, 0, 0);
}
// async global->LDS, 16B per lane. LDS dest is wave-uniform base + lane*16.
__device__ __forceinline__ void async16(const u16* g, u16* l) {
  __builtin_amdgcn_global_load_lds(
      (__attribute__((address_space(1))) void*)g,
      (__attribute__((address_space(3))) void*)l, 16, 0, 0);
}
#if __has_builtin(__builtin_amdgcn_exp2f)
#define EXP2(x) __builtin_amdgcn_exp2f(x)
#else
#define EXP2(x) exp2f(x)
#endif

#define VMC(n) asm volatile("s_waitcnt vmcnt(" #n ")" ::: "memory")
#define BAR __builtin_amdgcn_s_barrier()
#define P1 __builtin_amdgcn_s_setprio(1)
#define P0 __builtin_amdgcn_s_setprio(0)

// ---------------- fp32 -> bf16, all five tensors in one launch ---------------
// R11 post-mortem: fp32-direct GEMM staging spills registers (VGPR budget has
// no room for depth-2 reg staging); the separate streaming conversion is
// near HBM-bound (~452 MB) and stays.
__global__ __launch_bounds__(256) void conv_all(
    const float* __restrict__ hs, const float* __restrict__ wq,
    const float* __restrict__ wk, const float* __restrict__ wv,
    const float* __restrict__ wo, u16* __restrict__ dhs, u16* __restrict__ dwq,
    u16* __restrict__ dwk, u16* __restrict__ dwv, u16* __restrict__ dwo) {
  int i = blockIdx.x * 256 + threadIdx.x;
  const float* src;
  u16* dst;
  int off;
  if (i < 2097152) { src = hs; dst = dhs; off = 0; }
  else if (i < 6291456) { src = wq; dst = dwq; off = 2097152; }
  else if (i < 7340032) { src = wk; dst = dwk; off = 6291456; }
  else if (i < 8388608) { src = wv; dst = dwv; off = 7340032; }
  else { src = wo; dst = dwo; off = 8388608; }
  int j = i - off;
  float4 v = ((const float4*)src)[j];
  ushort4 o;
  o.x = f2bf(v.x); o.y = f2bf(v.y); o.z = f2bf(v.z); o.w = f2bf(v.w);
  ((ushort4*)dst)[j] = o;
}

// ---------------- 256xBN 4-phase GEMM, compiler-scheduled + setprio ---------
// C[M,N] = A[M,K] * B[N,K]^T.  BM=256, BN=NJ*64 (192 or 128), BK=64,
// 512 thr = 8 waves (4M x 2N, wave tile 64 x BN/2).  LDS dynamic:
// As[2][256][64] | Bs[2][BN][64] bf16, chunk-XOR swizzled on BOTH the
// pre-swizzled global source of global_load_lds (linear LDS dest) and the
// ds_read_b128 side.  R7-proven de-caged scheduling: barriers + counted VMC
// only, compiler inserts exact lgkm waits and interleaves staging into MFMA
// issue gaps.  NEW vs R7 (single variable): s_setprio(1) around the MFMA
// clusters (T5) -- phase-split + counted-vmcnt gives waves role diversity,
// the documented precondition for setprio to pay (m218b/m224).
// Counted VMC(4) at pre-ph2/pre-ph4 drains exactly the next tile; VMC(0)
// only in the tail iteration.
// Grid = 8 * (N/BN)  (M == 2048 -> 8 M-tiles, exact multiple of 8 XCDs).

#define DSA(dst, qi, d)                                                    \
  {                                                                        \
    const u16* p_ = As + (d)*16384 + (wm * 64 + (qi)*32 + cl) * 64;        \
    _Pragma("unroll") for (int ii = 0; ii < 2; ii++)                       \
        _Pragma("unroll") for (int kk = 0; kk < 2; kk++)                   \
            dst[ii][kk] =                                                  \
        *(const bf16x8*)(p_ + ii * 1024 + ((c0 ^ (kk << 2)) << 3));        \
  }

#define DSB(dst, qj, d)                                                    \
  {                                                                        \
    const u16* p_ =                                                        \
        Bs + (d)*BSTR + (wn * (BN / 2) + (qj) * (BN / 4) + cl) * 64;       \
    _Pragma("unroll") for (int jj = 0; jj < NJ; jj++)                      \
        _Pragma("unroll") for (int kk = 0; kk < 2; kk++)                   \
            dst[jj][kk] =                                                  \
        *(const bf16x8*)(p_ + jj * 1024 + ((c0 ^ (kk << 2)) << 3));        \
  }

// kk outermost: consecutive MFMAs hit distinct acc regs
#define MM(qi, qj, asrc, bsrc)                                             \
  {                                                                        \
    _Pragma("unroll") for (int kk = 0; kk < 2; kk++)                       \
        _Pragma("unroll") for (int ii = 0; ii < 2; ii++)                   \
            _Pragma("unroll") for (int jj = 0; jj < NJ; jj++)              \
                acc[(qi)*2 + ii][(qj)*NJ + jj] =                           \
        mfma16(asrc[ii][kk], bsrc[jj][kk], acc[(qi)*2 + ii][(qj)*NJ + jj]);\
  }

// one macro-phase: barrier pair + setprio hint around the MFMA cluster.
// NO sched_barrier / explicit lgkm: compiler schedules (R7 win).
#define PH2(MMA1, MMA2)                                          \
  {                                                              \
    BAR;                                                         \
    P1;                                                          \
    MMA1; MMA2;                                                  \
    P0;                                                          \
    BAR;                                                         \
  }

template <int NJ>
__global__ __launch_bounds__(512, 2) void gemm4p(
    const u16* __restrict__ A, const u16* __restrict__ B,
    u16* __restrict__ Cb, float* __restrict__ Cf, int N, int K) {
  constexpr int BN = NJ * 64;
  constexpr int BSTR = BN * 64;  // u16 per B dbuf
  extern __shared__ u16 lds[];
  u16* As = lds;           // [2][256*64]
  u16* Bs = lds + 32768;   // [2][BN*64]
  const int tid = threadIdx.x;
  const int lane = tid & 63, wv = tid >> 6;
  const int cl = lane & 15, qd = lane >> 4;
  const int wm = wv >> 1, wn = wv & 1;  // 4M x 2N waves
  const int c0 = qd ^ (cl & 7);

  // XCD-aware block swizzle (grid %8==0), decode M-fast (M-tiles == 8)
  const int cpx = gridDim.x >> 3;
  const int swz = (blockIdx.x & 7) * cpx + (blockIdx.x >> 3);
  const int m0 = (swz & 7) * 256;
  const int n0 = (swz >> 3) * BN;

  // per-lane staged-load source offsets (u16 elements); lane covers LDS
  // (row r, slot s), fetches global chunk c = s ^ (r&7)
  u32 aof[4], bof[NJ];
#pragma unroll
  for (int q = 0; q < 4; q++) {
    int r = q * 64 + wv * 8 + (lane >> 3);
    int c = (lane & 7) ^ (r & 7);
    aof[q] = (u32)(m0 + r) * K + c * 8;
  }
#pragma unroll
  for (int q = 0; q < NJ; q++) {
    int r = q * 64 + wv * 8 + (lane >> 3);
    int c = (lane & 7) ^ (r & 7);
    bof[q] = (u32)(n0 + r) * K + c * 8;
  }
  const int sbo = wv * 512;  // wave-uniform LDS stage offset

  auto STAll = [&](int tt, int d) {  // stage full A K-tile (4 loads)
#pragma unroll
    for (int q = 0; q < 4; q++)
      async16(A + (size_t)tt * 64 + aof[q], As + d * 16384 + q * 4096 + sbo);
  };
  auto STBall = [&](int tt, int d) {  // stage full B K-tile (NJ loads)
#pragma unroll
    for (int q = 0; q < NJ; q++)
      async16(B + (size_t)tt * 64 + bof[q], Bs + d * BSTR + q * 4096 + sbo);
  };

  f32x4 acc[4][2 * NJ];
  f32x4 zz = {0.f, 0.f, 0.f, 0.f};
#pragma unroll
  for (int i = 0; i < 4; i++)
#pragma unroll
    for (int j = 0; j < 2 * NJ; j++) acc[i][j] = zz;
  bf16x8 A0r[2][2], A1r[2][2], B0r[NJ][2], B1r[NJ][2];

  const int NT = K >> 6;  // 64-wide K-tiles; NT even, >= 4

  // prologue: t0 A+B -> dbuf0, t1 A -> dbuf1; drain t0 (t1A stays in flight)
  STAll(0, 0); STBall(0, 0); STAll(1, 1);
  VMC(4);
  BAR;

  for (int it = 0; it < (NT >> 1); ++it) {
    const int t = it * 2;          // tiles t (dbuf0), t+1 (dbuf1)
    const bool s2 = (t + 2) < NT;  // NT even => also guards t+3
    // pre-ph1: ds A0,A1,B0 (dbuf0) | stage (t+1)B -> dbuf1 (freed prev ph4)
    DSA(A0r, 0, 0); DSA(A1r, 1, 0); DSB(B0r, 0, 0);
    STBall(t + 1, 1);
    // ph1: tile t, left half-K
    PH2(MM(0, 0, A0r, B0r), MM(1, 0, A1r, B0r));
    // pre-ph2: ds B1 (dbuf0) | stage (t+2)A -> dbuf0 (A freed at ph1 exit)
    //          VMC(4): drains (t+1)A+B exactly, leaves (t+2)A in flight
    DSB(B1r, 1, 0);
    if (s2) {
      STAll(t + 2, 0);
      VMC(4);
    } else {
      VMC(0);
    }
    // ph2: tile t, right half-K
    PH2(MM(0, 1, A0r, B1r), MM(1, 1, A1r, B1r));
    // pre-ph3: ds A0,A1,B0 (dbuf1; visible: VMC@pre-ph2 + ph2 entry barrier)
    //          stage (t+2)B -> dbuf0 (B reads done at ph2 exit)
    DSA(A0r, 0, 1); DSA(A1r, 1, 1); DSB(B0r, 0, 1);
    if (s2) STBall(t + 2, 0);
    // ph3: tile t+1, left half-K
    PH2(MM(0, 0, A0r, B0r), MM(1, 0, A1r, B0r));
    // pre-ph4: ds B1 (dbuf1) | stage (t+3)A -> dbuf1 (A freed at ph3 exit)
    //          VMC(4): drains (t+2)A+B, leaves (t+3)A in flight
    DSB(B1r, 1, 1);
    if (s2) {
      STAll(t + 3, 1);
      VMC(4);
    } else {
      VMC(0);
    }
    // ph4: tile t+1, right half-K
    PH2(MM(0, 1, A0r, B1r), MM(1, 1, A1r, B1r));
  }

  // epilogue: C-write (C/D layout: col=lane&15, row=(lane>>4)*4+reg)
#pragma unroll
  for (int i = 0; i < 4; i++)
#pragma unroll
    for (int j = 0; j < 2 * NJ; j++) {
      int row = m0 + wm * 64 + i * 16 + qd * 4;
      int col = n0 + wn * (BN / 2) + (j / NJ) * (BN / 4) + (j % NJ) * 16 + cl;
#pragma unroll
      for (int r = 0; r < 4; r++) {
        float v = acc[i][j][r];
        if (Cb) Cb[(size_t)(row + r) * N + col] = f2bf(v);
        else    Cf[(size_t)(row + r) * N + col] = v;
      }
    }
}

// ---------------- fused RoPE + L2 norm (in place, bf16, strided) -------------
__global__ __launch_bounds__(256) void rope_l2norm(
    u16* __restrict__ x, const int* __restrict__ pos_ids,
    const float* __restrict__ scale, int hmask, int hshift, int stride) {
  const int lane = threadIdx.x & 63;
  const int wv = threadIdx.x >> 6;
  const int idx = blockIdx.x * 4 + wv;
  const int s = idx >> hshift;
  const int h = idx & hmask;
  u16* p = x + (size_t)s * stride + h * HD;
  const float pos = (float)pos_ids[s];
  const float inv = expf((float)lane * -0.20503692777194264f);  // 5e5^(-d/64)
  float sn, cs;
  sincosf(pos * inv, &sn, &cs);
  float a = bf2f(p[lane]);
  float b = bf2f(p[lane + 64]);
  float ra = a * cs - b * sn;
  float rb = b * cs + a * sn;
  float ss = ra * ra + rb * rb;
#pragma unroll
  for (int off = 32; off >= 1; off >>= 1) ss += __shfl_xor(ss, off, 64);
  float rd = 1.0f / (sqrtf(ss) + 1e-6f);
  p[lane] = f2bf(scale[lane] * ra * rd);
  p[lane + 64] = f2bf(scale[lane + 64] * rb * rd);
}

// ---------------- V transpose: qkv V-cols [2048][1024@QS] -> [1024][2048] ----
__global__ __launch_bounds__(256) void transpose_v(const u16* __restrict__ v,
                                                   u16* __restrict__ vt) {
  __shared__ u16 t[64][65];
  const int r = threadIdx.x >> 6;
  const int c = threadIdx.x & 63;
  const int s0 = blockIdx.x * 64, d0 = blockIdx.y * 64;
#pragma unroll
  for (int i = 0; i < 16; i++) {
    int row = i * 4 + r;
    t[row][c] = v[(size_t)(s0 + row) * QS + d0 + c];
  }
  __syncthreads();
#pragma unroll
  for (int i = 0; i < 16; i++) {
    int row = i * 4 + r;
    vt[(size_t)(d0 + row) * S_LEN + s0 + c] = t[c][row];
  }
}

// ---------------- causal flash attention, Q-tile 128, 8 waves ----------------
// Work-balanced (qbi, 15-qbi) pairs, grid 8 x 32 = 256 blocks = 1/CU.
// K/V double-buffered in dynamic LDS; stage(kt+1) issued BEFORE compute(kt);
// one vmcnt(0)+barrier per tile.  No sched fences (compiler-scheduled).
#define PLD 68

__global__ __launch_bounds__(512) void flash_attn(
    const u16* __restrict__ QKV, const u16* __restrict__ Vt,
    u16* __restrict__ O) {
  extern __shared__ u16 alds[];
  u16* Ks = alds;           // [2][64*128]  slot = row*16 + (g ^ (row&15))
  u16* Vs = alds + 16384;   // [2][128*64]  slot = row*8  + (g ^ (row&7))
  u16* Ps = alds + 32768;   // [128][PLD]
  const int tid = threadIdx.x;
  const int lane = tid & 63, wv = tid >> 6;  // wv in [0,8)
  const int cl = lane & 15, qd = lane >> 4;
  const int h = blockIdx.y;
  const int kvh = h >> 2;
  const float es = 0.12751629240081506f;  // (1/sqrt(128)) * log2(e)

  const u16* Kbase = QKV + 4096 + kvh * HD;          // key rows, stride QS
  const u16* Vbase = Vt + (size_t)kvh * HD * S_LEN;  // [d][s], stride S_LEN

  auto stage = [&](int kt, int d) {
#pragma unroll
    for (int q = 0; q < 2; q++) {
      int c = q * 512 + wv * 64 + lane;
      int kr = c >> 4, kg = (c & 15) ^ (kr & 15);
      async16(Kbase + (size_t)(kt * 64 + kr) * QS + kg * 8,
              Ks + d * 8192 + (q * 512 + wv * 64) * 8);
      int vr = c >> 3, vg = (c & 7) ^ (vr & 7);
      async16(Vbase + (size_t)vr * S_LEN + kt * 64 + vg * 8,
              Vs + d * 8192 + (q * 512 + wv * 64) * 8);
    }
  };

  for (int half = 0; half < 2; half++) {
    const int qbi = half ? (15 - (int)blockIdx.x) : (int)blockIdx.x;
    const int q0 = qbi * 128;

    // Q fragments straight from global; wave wv owns q-rows q0+wv*16 .. +15
    bf16x8 aQ[4];
    {
      const u16* qrow =
          QKV + (size_t)(q0 + wv * 16 + cl) * QS + h * HD + qd * 8;
#pragma unroll
      for (int kk = 0; kk < 4; kk++) aQ[kk] = *(const bf16x8*)(qrow + kk * 32);
    }

    f32x4 oacc[8];
    f32x4 zz = {0.f, 0.f, 0.f, 0.f};
#pragma unroll
    for (int n = 0; n < 8; n++) oacc[n] = zz;
    float lsum[4] = {0.f, 0.f, 0.f, 0.f};

    const int row_min = q0 + wv * 16;
    const int ktmax = 2 * qbi + 1;  // >= 1 always

    int cur = 0;
    stage(0, 0);
    for (int kt = 0; kt <= ktmax; kt++) {
      if (kt < ktmax) stage(kt + 1, cur ^ 1);  // issue-early
      if (kt == 0) {
        VMC(4);  // tile0 landed; tile1's 4 loads stay in flight
        BAR;
      }
      const int koff = cur * 8192;

      if (kt * 64 <= row_min + 15) {  // wave not fully above the diagonal
        // S = Q K^T (this wave: 16 q-rows x 64 keys); kk outer -> indep runs
        f32x4 sacc[4];
#pragma unroll
        for (int j = 0; j < 4; j++) sacc[j] = zz;
#pragma unroll
        for (int kk = 0; kk < 4; kk++) {
#pragma unroll
          for (int j = 0; j < 4; j++) {
            int row = j * 16 + cl;
            int ch = (kk * 4 + qd) ^ (row & 15);
            bf16x8 bK = *(const bf16x8*)&Ks[koff + row * 128 + ch * 8];
            sacc[j] = mfma16(aQ[kk], bK, sacc[j]);
          }
        }

        float pm[4][4];
        if (kt * 64 + 63 > row_min) {  // diagonal tile: causal mask
          const int grow = row_min + qd * 4;
#pragma unroll
          for (int j = 0; j < 4; j++) {
            int gcol = kt * 64 + j * 16 + cl;
#pragma unroll
            for (int r = 0; r < 4; r++)
              pm[j][r] = (gcol <= grow + r) ? EXP2(sacc[j][r] * es) : 0.f;
          }
        } else {
#pragma unroll
          for (int j = 0; j < 4; j++)
#pragma unroll
            for (int r = 0; r < 4; r++) pm[j][r] = EXP2(sacc[j][r] * es);
        }
#pragma unroll
        for (int j = 0; j < 4; j++)
#pragma unroll
          for (int r = 0; r < 4; r++) lsum[r] += pm[j][r];

        // P: C-layout -> LDS (A-layout); wave-private strip, no block barrier
#pragma unroll
        for (int j = 0; j < 4; j++)
#pragma unroll
          for (int r = 0; r < 4; r++)
            Ps[(wv * 16 + qd * 4 + r) * PLD + j * 16 + cl] = f2bf(pm[j][r]);
        __asm__ volatile("s_waitcnt lgkmcnt(0)" ::: "memory");  // cross-lane

        // O += P V (n inner: dep distance 8)
#pragma unroll
        for (int kk = 0; kk < 2; kk++) {
          bf16x8 aP =
              *(const bf16x8*)&Ps[(wv * 16 + cl) * PLD + kk * 32 + qd * 8];
#pragma unroll
          for (int n = 0; n < 8; n++) {
            int row = n * 16 + cl;
            int ch = (kk * 4 + qd) ^ (row & 7);
            bf16x8 bV = *(const bf16x8*)&Vs[koff + row * 64 + ch * 8];
            oacc[n] = mfma16(aP, bV, oacc[n]);
          }
        }
      }

      VMC(0);  // stage(kt+1) drained (latency hidden under compute)
      BAR;
      cur ^= 1;
    }

    // reduce row sums across the 16-lane column group, write O
#pragma unroll
    for (int r = 0; r < 4; r++) {
#pragma unroll
      for (int off = 8; off >= 1; off >>= 1)
        lsum[r] += __shfl_xor(lsum[r], off, 64);
    }
#pragma unroll
    for (int r = 0; r < 4; r++) {
      float il = 1.0f / lsum[r];
      int row = row_min + qd * 4 + r;
#pragma unroll
      for (int n = 0; n < 8; n++)
        O[(size_t)row * HID + h * HD + n * 16 + cl] = f2bf(oacc[n][r] * il);
    }
  }
}

// ---------------- launch ----------------
extern "C" void kernel_launch(void* const* d_in, const int* in_sizes, int n_in,
                              void* d_out, int out_size, void* d_ws, size_t ws_size,
                              hipStream_t stream) {
  const float* hs = (const float*)d_in[0];
  const int* pos = (const int*)d_in[1];
  const float* Wq = (const float*)d_in[2];
  const float* Wk = (const float*)d_in[3];
  const float* Wv = (const float*)d_in[4];
  const float* Wo = (const float*)d_in[5];
  const float* qsc = (const float*)d_in[6];
  const float* ksc = (const float*)d_in[7];
  float* out = (float*)d_out;
  char* ws = (char*)d_ws;
  const size_t MB = 1u << 20;

  u16* hs_b  = (u16*)(ws + 0 * MB);   // 16 MB; reused for attention output
  u16* wq_b  = (u16*)(ws + 16 * MB);  // 32 MB  } wq|wk|wv contiguous ->
  u16* wk_b  = (u16*)(ws + 48 * MB);  // 8 MB   }   B[6144][4096]
  u16* wv_b  = (u16*)(ws + 56 * MB);  // 8 MB   }
  u16* qkv_b = (u16*)(ws + 64 * MB);  // 24 MB: [2048][6144] = Q|K|V
  u16* vt_b  = (u16*)(ws + 88 * MB);  // 4 MB: V^T [1024][2048]
  u16* wo_b  = (u16*)(ws + 92 * MB);  // 32 MB
  u16* o_b   = hs_b;                  // hs dead after qkv gemm

  static bool attr_set = false;
  if (!attr_set) {
    hipFuncSetAttribute(reinterpret_cast<const void*>(&gemm4p<3>),
                        hipFuncAttributeMaxDynamicSharedMemorySize, 114688);
    hipFuncSetAttribute(reinterpret_cast<const void*>(&gemm4p<2>),
                        hipFuncAttributeMaxDynamicSharedMemorySize, 98304);
    hipFuncSetAttribute(reinterpret_cast<const void*>(&flash_attn),
                        hipFuncAttributeMaxDynamicSharedMemorySize, 82944);
    attr_set = true;
  }

  conv_all<<<49152, 256, 0, stream>>>(hs, Wq, Wk, Wv, Wo,
                                      hs_b, wq_b, wk_b, wv_b, wo_b);

  // fused QKV projection: [2048][4096] x [6144][4096]^T -> [2048][6144]
  // BN=192 -> grid 8 x 32 = 256 blocks = 1/CU exactly
  gemm4p<3><<<dim3(8 * (QS / 192)), 512, 114688, stream>>>(
      hs_b, wq_b, qkv_b, nullptr, QS, HID);

  rope_l2norm<<<S_LEN * NH / 4, 256, 0, stream>>>(qkv_b, pos, qsc, NH - 1, 5, QS);
  rope_l2norm<<<S_LEN * NKV / 4, 256, 0, stream>>>(qkv_b + 4096, pos, ksc, NKV - 1, 3, QS);
  transpose_v<<<dim3(S_LEN / 64, (NKV * HD) / 64), 256, 0, stream>>>(qkv_b + 5120, vt_b);

  flash_attn<<<dim3(8, NH), 512, 82944, stream>>>(qkv_b, vt_b, o_b);

  // output projection: [2048][4096] x [4096][4096]^T -> f32 out
  // BN=128 -> grid 8 x 32 = 256 blocks = 1/CU exactly
  gemm4p<2><<<dim3(8 * (HID / 128)), 512, 98304, stream>>>(
      o_b, wo_b, nullptr, out, HID, HID);
}

// Round 13
// 437.604 us; speedup vs baseline: 1.7343x; 1.0402x over previous
//
#include <hip/hip_runtime.h>
#include <math.h>

typedef unsigned short u16;
typedef unsigned int u32;
typedef __attribute__((ext_vector_type(8))) short bf16x8;
typedef __attribute__((ext_vector_type(4))) float f32x4;

#define S_LEN 2048
#define HID 4096
#define NH 32
#define NKV 8
#define HD 128
#define QS 6144  // fused qkv row stride (4096 Q | 1024 K | 1024 V)

__device__ __forceinline__ u16 f2bf(float f) {
  u32 u = __float_as_uint(f);
  u32 r = (u + 0x7FFFu + ((u >> 16) & 1u)) >> 16;
  return (u16)r;
}
__device__ __forceinline__ float bf2f(u16 v) {
  return __uint_as_float(((u32)v) << 16);
}
__device__ __forceinline__ f32x4 mfma16(bf16x8 a, bf16x8 b, f32x4 c) {
  return __builtin_amdgcn_mfma_f32_16x16x32_bf16(a, b, c, 0, 0, 0);
}
// async global->LDS, 16B per lane. LDS dest is wave-uniform base + lane*16.
__device__ __forceinline__ void async16(const u16* g, u16* l) {
  __builtin_amdgcn_global_load_lds(
      (__attribute__((address_space(1))) void*)g,
      (__attribute__((address_space(3))) void*)l, 16, 0, 0);
}
#if __has_builtin(__builtin_amdgcn_exp2f)
#define EXP2(x) __builtin_amdgcn_exp2f(x)
#else
#define EXP2(x) exp2f(x)
#endif

#define VMC(n) asm volatile("s_waitcnt vmcnt(" #n ")" ::: "memory")
#define BAR __builtin_amdgcn_s_barrier()

// ---------------- fp32 -> bf16, all five tensors in one launch ---------------
// fp32-direct GEMM staging spills registers (R9/R11); this streaming
// conversion is near HBM-bound (~301 MB) and stays.
__global__ __launch_bounds__(256) void conv_all(
    const float* __restrict__ hs, const float* __restrict__ wq,
    const float* __restrict__ wk, const float* __restrict__ wv,
    const float* __restrict__ wo, u16* __restrict__ dhs, u16* __restrict__ dwq,
    u16* __restrict__ dwk, u16* __restrict__ dwv, u16* __restrict__ dwo) {
  int i = blockIdx.x * 256 + threadIdx.x;
  const float* src;
  u16* dst;
  int off;
  if (i < 2097152) { src = hs; dst = dhs; off = 0; }
  else if (i < 6291456) { src = wq; dst = dwq; off = 2097152; }
  else if (i < 7340032) { src = wk; dst = dwk; off = 6291456; }
  else if (i < 8388608) { src = wv; dst = dwv; off = 7340032; }
  else { src = wo; dst = dwo; off = 8388608; }
  int j = i - off;
  float4 v = ((const float4*)src)[j];
  ushort4 o;
  o.x = f2bf(v.x); o.y = f2bf(v.y); o.z = f2bf(v.z); o.w = f2bf(v.w);
  ((ushort4*)dst)[j] = o;
}

// ---------------- 256xBN 4-phase GEMM, compiler-scheduled (R7 exact) --------
// C[M,N] = A[M,K] * B[N,K]^T.  BM=256, BN=NJ*64 (192 or 128), BK=64,
// 512 thr = 8 waves (4M x 2N, wave tile 64 x BN/2).  LDS dynamic:
// As[2][256][64] | Bs[2][BN][64] bf16, chunk-XOR swizzled on BOTH the
// pre-swizzled global source of global_load_lds (linear LDS dest) and the
// ds_read_b128 side.  De-caged scheduling (R7 win, session best): barriers
// + counted VMC only; compiler inserts exact lgkm waits and interleaves
// staging/addressing into MFMA issue gaps.  R12 verdict: setprio on this
// structure is a ~12% REGRESSION (lockstep waves; the hint starves the
// co-scheduled staging work) -- keep it out.
// Counted VMC(4) at pre-ph2/pre-ph4 drains exactly the next tile; VMC(0)
// only in the tail iteration.
// Grid = 8 * (N/BN)  (M == 2048 -> 8 M-tiles, exact multiple of 8 XCDs).

#define DSA(dst, qi, d)                                                    \
  {                                                                        \
    const u16* p_ = As + (d)*16384 + (wm * 64 + (qi)*32 + cl) * 64;        \
    _Pragma("unroll") for (int ii = 0; ii < 2; ii++)                       \
        _Pragma("unroll") for (int kk = 0; kk < 2; kk++)                   \
            dst[ii][kk] =                                                  \
        *(const bf16x8*)(p_ + ii * 1024 + ((c0 ^ (kk << 2)) << 3));        \
  }

#define DSB(dst, qj, d)                                                    \
  {                                                                        \
    const u16* p_ =                                                        \
        Bs + (d)*BSTR + (wn * (BN / 2) + (qj) * (BN / 4) + cl) * 64;       \
    _Pragma("unroll") for (int jj = 0; jj < NJ; jj++)                      \
        _Pragma("unroll") for (int kk = 0; kk < 2; kk++)                   \
            dst[jj][kk] =                                                  \
        *(const bf16x8*)(p_ + jj * 1024 + ((c0 ^ (kk << 2)) << 3));        \
  }

// kk outermost: consecutive MFMAs hit distinct acc regs
#define MM(qi, qj, asrc, bsrc)                                             \
  {                                                                        \
    _Pragma("unroll") for (int kk = 0; kk < 2; kk++)                       \
        _Pragma("unroll") for (int ii = 0; ii < 2; ii++)                   \
            _Pragma("unroll") for (int jj = 0; jj < NJ; jj++)              \
                acc[(qi)*2 + ii][(qj)*NJ + jj] =                           \
        mfma16(asrc[ii][kk], bsrc[jj][kk], acc[(qi)*2 + ii][(qj)*NJ + jj]);\
  }

// one macro-phase: just the barrier pair around the MFMA cluster.
#define PH2(MMA1, MMA2)                                          \
  {                                                              \
    BAR;                                                         \
    MMA1; MMA2;                                                  \
    BAR;                                                         \
  }

template <int NJ>
__global__ __launch_bounds__(512, 2) void gemm4p(
    const u16* __restrict__ A, const u16* __restrict__ B,
    u16* __restrict__ Cb, float* __restrict__ Cf, int N, int K) {
  constexpr int BN = NJ * 64;
  constexpr int BSTR = BN * 64;  // u16 per B dbuf
  extern __shared__ u16 lds[];
  u16* As = lds;           // [2][256*64]
  u16* Bs = lds + 32768;   // [2][BN*64]
  const int tid = threadIdx.x;
  const int lane = tid & 63, wv = tid >> 6;
  const int cl = lane & 15, qd = lane >> 4;
  const int wm = wv >> 1, wn = wv & 1;  // 4M x 2N waves
  const int c0 = qd ^ (cl & 7);

  // XCD-aware block swizzle (grid %8==0), decode M-fast (M-tiles == 8)
  const int cpx = gridDim.x >> 3;
  const int swz = (blockIdx.x & 7) * cpx + (blockIdx.x >> 3);
  const int m0 = (swz & 7) * 256;
  const int n0 = (swz >> 3) * BN;

  // per-lane staged-load source offsets (u16 elements); lane covers LDS
  // (row r, slot s), fetches global chunk c = s ^ (r&7)
  u32 aof[4], bof[NJ];
#pragma unroll
  for (int q = 0; q < 4; q++) {
    int r = q * 64 + wv * 8 + (lane >> 3);
    int c = (lane & 7) ^ (r & 7);
    aof[q] = (u32)(m0 + r) * K + c * 8;
  }
#pragma unroll
  for (int q = 0; q < NJ; q++) {
    int r = q * 64 + wv * 8 + (lane >> 3);
    int c = (lane & 7) ^ (r & 7);
    bof[q] = (u32)(n0 + r) * K + c * 8;
  }
  const int sbo = wv * 512;  // wave-uniform LDS stage offset

  auto STAll = [&](int tt, int d) {  // stage full A K-tile (4 loads)
#pragma unroll
    for (int q = 0; q < 4; q++)
      async16(A + (size_t)tt * 64 + aof[q], As + d * 16384 + q * 4096 + sbo);
  };
  auto STBall = [&](int tt, int d) {  // stage full B K-tile (NJ loads)
#pragma unroll
    for (int q = 0; q < NJ; q++)
      async16(B + (size_t)tt * 64 + bof[q], Bs + d * BSTR + q * 4096 + sbo);
  };

  f32x4 acc[4][2 * NJ];
  f32x4 zz = {0.f, 0.f, 0.f, 0.f};
#pragma unroll
  for (int i = 0; i < 4; i++)
#pragma unroll
    for (int j = 0; j < 2 * NJ; j++) acc[i][j] = zz;
  bf16x8 A0r[2][2], A1r[2][2], B0r[NJ][2], B1r[NJ][2];

  const int NT = K >> 6;  // 64-wide K-tiles; NT even, >= 4

  // prologue: t0 A+B -> dbuf0, t1 A -> dbuf1; drain t0 (t1A stays in flight)
  STAll(0, 0); STBall(0, 0); STAll(1, 1);
  VMC(4);
  BAR;

  for (int it = 0; it < (NT >> 1); ++it) {
    const int t = it * 2;          // tiles t (dbuf0), t+1 (dbuf1)
    const bool s2 = (t + 2) < NT;  // NT even => also guards t+3
    // pre-ph1: ds A0,A1,B0 (dbuf0) | stage (t+1)B -> dbuf1 (freed prev ph4)
    DSA(A0r, 0, 0); DSA(A1r, 1, 0); DSB(B0r, 0, 0);
    STBall(t + 1, 1);
    // ph1: tile t, left half-K
    PH2(MM(0, 0, A0r, B0r), MM(1, 0, A1r, B0r));
    // pre-ph2: ds B1 (dbuf0) | stage (t+2)A -> dbuf0 (A freed at ph1 exit)
    //          VMC(4): drains (t+1)A+B exactly, leaves (t+2)A in flight
    DSB(B1r, 1, 0);
    if (s2) {
      STAll(t + 2, 0);
      VMC(4);
    } else {
      VMC(0);
    }
    // ph2: tile t, right half-K
    PH2(MM(0, 1, A0r, B1r), MM(1, 1, A1r, B1r));
    // pre-ph3: ds A0,A1,B0 (dbuf1; visible: VMC@pre-ph2 + ph2 entry barrier)
    //          stage (t+2)B -> dbuf0 (B reads done at ph2 exit)
    DSA(A0r, 0, 1); DSA(A1r, 1, 1); DSB(B0r, 0, 1);
    if (s2) STBall(t + 2, 0);
    // ph3: tile t+1, left half-K
    PH2(MM(0, 0, A0r, B0r), MM(1, 0, A1r, B0r));
    // pre-ph4: ds B1 (dbuf1) | stage (t+3)A -> dbuf1 (A freed at ph3 exit)
    //          VMC(4): drains (t+2)A+B, leaves (t+3)A in flight
    DSB(B1r, 1, 1);
    if (s2) {
      STAll(t + 3, 1);
      VMC(4);
    } else {
      VMC(0);
    }
    // ph4: tile t+1, right half-K
    PH2(MM(0, 1, A0r, B1r), MM(1, 1, A1r, B1r));
  }

  // epilogue: C-write (C/D layout: col=lane&15, row=(lane>>4)*4+reg)
#pragma unroll
  for (int i = 0; i < 4; i++)
#pragma unroll
    for (int j = 0; j < 2 * NJ; j++) {
      int row = m0 + wm * 64 + i * 16 + qd * 4;
      int col = n0 + wn * (BN / 2) + (j / NJ) * (BN / 4) + (j % NJ) * 16 + cl;
#pragma unroll
      for (int r = 0; r < 4; r++) {
        float v = acc[i][j][r];
        if (Cb) Cb[(size_t)(row + r) * N + col] = f2bf(v);
        else    Cf[(size_t)(row + r) * N + col] = v;
      }
    }
}

// ------- merged postprocess: rope+L2norm (Q rows | K rows) + V transpose ----
// Replaces 3 launches with 1.  Block-uniform branch on blockIdx.x:
//   [0, 16384)          : rope Q  (4 row-heads/block, 1 per wave)
//   [16384, 20480)      : rope K
//   [20480, 20992)      : V transpose (64x64 tile per block)
// rope math identical to the previous rope_l2norm; transpose identical to
// the previous transpose_v.
#define RQ_BLKS 16384   // 2048*32/4
#define RK_BLKS 4096    // 2048*8/4
#define TV_BLKS 512     // (2048/64) * (1024/64)

__global__ __launch_bounds__(256) void postproc(
    u16* __restrict__ qkv, const int* __restrict__ pos_ids,
    const float* __restrict__ qsc, const float* __restrict__ ksc,
    u16* __restrict__ vt) {
  __shared__ u16 t[64][65];
  const int bid = blockIdx.x;
  if (bid < RQ_BLKS + RK_BLKS) {
    // ---- rope + L2 norm ----
    const int lane = threadIdx.x & 63;
    const int wv = threadIdx.x >> 6;
    int s, hoff;
    const float* scale;
    if (bid < RQ_BLKS) {
      int idx = bid * 4 + wv;           // q: 2048*32 row-heads
      s = idx >> 5;
      hoff = (idx & 31) * HD;
      scale = qsc;
    } else {
      int idx = (bid - RQ_BLKS) * 4 + wv;  // k: 2048*8 row-heads
      s = idx >> 3;
      hoff = 4096 + (idx & 7) * HD;
      scale = ksc;
    }
    u16* p = qkv + (size_t)s * QS + hoff;
    const float pos = (float)pos_ids[s];
    const float inv = expf((float)lane * -0.20503692777194264f);  // 5e5^(-d/64)
    float sn, cs;
    sincosf(pos * inv, &sn, &cs);
    float a = bf2f(p[lane]);
    float b = bf2f(p[lane + 64]);
    float ra = a * cs - b * sn;
    float rb = b * cs + a * sn;
    float ss = ra * ra + rb * rb;
#pragma unroll
    for (int off = 32; off >= 1; off >>= 1) ss += __shfl_xor(ss, off, 64);
    float rd = 1.0f / (sqrtf(ss) + 1e-6f);
    p[lane] = f2bf(scale[lane] * ra * rd);
    p[lane + 64] = f2bf(scale[lane + 64] * rb * rd);
  } else {
    // ---- V transpose: qkv V-cols [2048][1024@QS] -> vt [1024][2048] ----
    const int tb = bid - (RQ_BLKS + RK_BLKS);
    const int s0 = (tb & 31) * 64;       // 32 s-tiles
    const int d0 = (tb >> 5) * 64;       // 16 d-tiles
    const int r = threadIdx.x >> 6;
    const int c = threadIdx.x & 63;
    const u16* v = qkv + 5120;
#pragma unroll
    for (int i = 0; i < 16; i++) {
      int row = i * 4 + r;
      t[row][c] = v[(size_t)(s0 + row) * QS + d0 + c];
    }
    __syncthreads();
#pragma unroll
    for (int i = 0; i < 16; i++) {
      int row = i * 4 + r;
      vt[(size_t)(d0 + row) * S_LEN + s0 + c] = t[c][row];
    }
  }
}

// ---------------- causal flash attention, Q-tile 128, 8 waves ----------------
// Work-balanced (qbi, 15-qbi) pairs, grid 8 x 32 = 256 blocks = 1/CU.
// K/V double-buffered in dynamic LDS; stage(kt+1) issued BEFORE compute(kt);
// one vmcnt(0)+barrier per tile.  No sched fences (compiler-scheduled).
#define PLD 68

__global__ __launch_bounds__(512) void flash_attn(
    const u16* __restrict__ QKV, const u16* __restrict__ Vt,
    u16* __restrict__ O) {
  extern __shared__ u16 alds[];
  u16* Ks = alds;           // [2][64*128]  slot = row*16 + (g ^ (row&15))
  u16* Vs = alds + 16384;   // [2][128*64]  slot = row*8  + (g ^ (row&7))
  u16* Ps = alds + 32768;   // [128][PLD]
  const int tid = threadIdx.x;
  const int lane = tid & 63, wv = tid >> 6;  // wv in [0,8)
  const int cl = lane & 15, qd = lane >> 4;
  const int h = blockIdx.y;
  const int kvh = h >> 2;
  const float es = 0.12751629240081506f;  // (1/sqrt(128)) * log2(e)

  const u16* Kbase = QKV + 4096 + kvh * HD;          // key rows, stride QS
  const u16* Vbase = Vt + (size_t)kvh * HD * S_LEN;  // [d][s], stride S_LEN

  auto stage = [&](int kt, int d) {
#pragma unroll
    for (int q = 0; q < 2; q++) {
      int c = q * 512 + wv * 64 + lane;
      int kr = c >> 4, kg = (c & 15) ^ (kr & 15);
      async16(Kbase + (size_t)(kt * 64 + kr) * QS + kg * 8,
              Ks + d * 8192 + (q * 512 + wv * 64) * 8);
      int vr = c >> 3, vg = (c & 7) ^ (vr & 7);
      async16(Vbase + (size_t)vr * S_LEN + kt * 64 + vg * 8,
              Vs + d * 8192 + (q * 512 + wv * 64) * 8);
    }
  };

  for (int half = 0; half < 2; half++) {
    const int qbi = half ? (15 - (int)blockIdx.x) : (int)blockIdx.x;
    const int q0 = qbi * 128;

    // Q fragments straight from global; wave wv owns q-rows q0+wv*16 .. +15
    bf16x8 aQ[4];
    {
      const u16* qrow =
          QKV + (size_t)(q0 + wv * 16 + cl) * QS + h * HD + qd * 8;
#pragma unroll
      for (int kk = 0; kk < 4; kk++) aQ[kk] = *(const bf16x8*)(qrow + kk * 32);
    }

    f32x4 oacc[8];
    f32x4 zz = {0.f, 0.f, 0.f, 0.f};
#pragma unroll
    for (int n = 0; n < 8; n++) oacc[n] = zz;
    float lsum[4] = {0.f, 0.f, 0.f, 0.f};

    const int row_min = q0 + wv * 16;
    const int ktmax = 2 * qbi + 1;  // >= 1 always

    int cur = 0;
    stage(0, 0);
    for (int kt = 0; kt <= ktmax; kt++) {
      if (kt < ktmax) stage(kt + 1, cur ^ 1);  // issue-early
      if (kt == 0) {
        VMC(4);  // tile0 landed; tile1's 4 loads stay in flight
        BAR;
      }
      const int koff = cur * 8192;

      if (kt * 64 <= row_min + 15) {  // wave not fully above the diagonal
        // S = Q K^T (this wave: 16 q-rows x 64 keys); kk outer -> indep runs
        f32x4 sacc[4];
#pragma unroll
        for (int j = 0; j < 4; j++) sacc[j] = zz;
#pragma unroll
        for (int kk = 0; kk < 4; kk++) {
#pragma unroll
          for (int j = 0; j < 4; j++) {
            int row = j * 16 + cl;
            int ch = (kk * 4 + qd) ^ (row & 15);
            bf16x8 bK = *(const bf16x8*)&Ks[koff + row * 128 + ch * 8];
            sacc[j] = mfma16(aQ[kk], bK, sacc[j]);
          }
        }

        float pm[4][4];
        if (kt * 64 + 63 > row_min) {  // diagonal tile: causal mask
          const int grow = row_min + qd * 4;
#pragma unroll
          for (int j = 0; j < 4; j++) {
            int gcol = kt * 64 + j * 16 + cl;
#pragma unroll
            for (int r = 0; r < 4; r++)
              pm[j][r] = (gcol <= grow + r) ? EXP2(sacc[j][r] * es) : 0.f;
          }
        } else {
#pragma unroll
          for (int j = 0; j < 4; j++)
#pragma unroll
            for (int r = 0; r < 4; r++) pm[j][r] = EXP2(sacc[j][r] * es);
        }
#pragma unroll
        for (int j = 0; j < 4; j++)
#pragma unroll
          for (int r = 0; r < 4; r++) lsum[r] += pm[j][r];

        // P: C-layout -> LDS (A-layout); wave-private strip, no block barrier
#pragma unroll
        for (int j = 0; j < 4; j++)
#pragma unroll
          for (int r = 0; r < 4; r++)
            Ps[(wv * 16 + qd * 4 + r) * PLD + j * 16 + cl] = f2bf(pm[j][r]);
        __asm__ volatile("s_waitcnt lgkmcnt(0)" ::: "memory");  // cross-lane

        // O += P V (n inner: dep distance 8)
#pragma unroll
        for (int kk = 0; kk < 2; kk++) {
          bf16x8 aP =
              *(const bf16x8*)&Ps[(wv * 16 + cl) * PLD + kk * 32 + qd * 8];
#pragma unroll
          for (int n = 0; n < 8; n++) {
            int row = n * 16 + cl;
            int ch = (kk * 4 + qd) ^ (row & 7);
            bf16x8 bV = *(const bf16x8*)&Vs[koff + row * 64 + ch * 8];
            oacc[n] = mfma16(aP, bV, oacc[n]);
          }
        }
      }

      VMC(0);  // stage(kt+1) drained (latency hidden under compute)
      BAR;
      cur ^= 1;
    }

    // reduce row sums across the 16-lane column group, write O
#pragma unroll
    for (int r = 0; r < 4; r++) {
#pragma unroll
      for (int off = 8; off >= 1; off >>= 1)
        lsum[r] += __shfl_xor(lsum[r], off, 64);
    }
#pragma unroll
    for (int r = 0; r < 4; r++) {
      float il = 1.0f / lsum[r];
      int row = row_min + qd * 4 + r;
#pragma unroll
      for (int n = 0; n < 8; n++)
        O[(size_t)row * HID + h * HD + n * 16 + cl] = f2bf(oacc[n][r] * il);
    }
  }
}

// ---------------- launch ----------------
extern "C" void kernel_launch(void* const* d_in, const int* in_sizes, int n_in,
                              void* d_out, int out_size, void* d_ws, size_t ws_size,
                              hipStream_t stream) {
  const float* hs = (const float*)d_in[0];
  const int* pos = (const int*)d_in[1];
  const float* Wq = (const float*)d_in[2];
  const float* Wk = (const float*)d_in[3];
  const float* Wv = (const float*)d_in[4];
  const float* Wo = (const float*)d_in[5];
  const float* qsc = (const float*)d_in[6];
  const float* ksc = (const float*)d_in[7];
  float* out = (float*)d_out;
  char* ws = (char*)d_ws;
  const size_t MB = 1u << 20;

  u16* hs_b  = (u16*)(ws + 0 * MB);   // 16 MB; reused for attention output
  u16* wq_b  = (u16*)(ws + 16 * MB);  // 32 MB  } wq|wk|wv contiguous ->
  u16* wk_b  = (u16*)(ws + 48 * MB);  // 8 MB   }   B[6144][4096]
  u16* wv_b  = (u16*)(ws + 56 * MB);  // 8 MB   }
  u16* qkv_b = (u16*)(ws + 64 * MB);  // 24 MB: [2048][6144] = Q|K|V
  u16* vt_b  = (u16*)(ws + 88 * MB);  // 4 MB: V^T [1024][2048]
  u16* wo_b  = (u16*)(ws + 92 * MB);  // 32 MB
  u16* o_b   = hs_b;                  // hs dead after qkv gemm

  static bool attr_set = false;
  if (!attr_set) {
    hipFuncSetAttribute(reinterpret_cast<const void*>(&gemm4p<3>),
                        hipFuncAttributeMaxDynamicSharedMemorySize, 114688);
    hipFuncSetAttribute(reinterpret_cast<const void*>(&gemm4p<2>),
                        hipFuncAttributeMaxDynamicSharedMemorySize, 98304);
    hipFuncSetAttribute(reinterpret_cast<const void*>(&flash_attn),
                        hipFuncAttributeMaxDynamicSharedMemorySize, 82944);
    attr_set = true;
  }

  conv_all<<<49152, 256, 0, stream>>>(hs, Wq, Wk, Wv, Wo,
                                      hs_b, wq_b, wk_b, wv_b, wo_b);

  // fused QKV projection: [2048][4096] x [6144][4096]^T -> [2048][6144]
  // BN=192 -> grid 8 x 32 = 256 blocks = 1/CU exactly
  gemm4p<3><<<dim3(8 * (QS / 192)), 512, 114688, stream>>>(
      hs_b, wq_b, qkv_b, nullptr, QS, HID);

  // merged rope(Q) + rope(K) + V-transpose (was 3 launches)
  postproc<<<RQ_BLKS + RK_BLKS + TV_BLKS, 256, 0, stream>>>(
      qkv_b, pos, qsc, ksc, vt_b);

  flash_attn<<<dim3(8, NH), 512, 82944, stream>>>(qkv_b, vt_b, o_b);

  // output projection: [2048][4096] x [4096][4096]^T -> f32 out
  // BN=128 -> grid 8 x 32 = 256 blocks = 1/CU exactly
  gemm4p<2><<<dim3(8 * (HID / 128)), 512, 98304, stream>>>(
      o_b, wo_b, nullptr, out, HID, HID);
}